// Round 1
// baseline (245.071 us; speedup 1.0000x reference)
//
#include <hip/hip_runtime.h>
#include <math.h>

#define NN 3072
#define NH 8
#define FO 64
#define FCAT (NH * FO)   /* 512 */
#define MAXDEG 128
#define ALPHA 0.2f

// ---------------- CSR build: one wave per row, ballot-ordered (deterministic) ----------------
__global__ __launch_bounds__(64) void build_csr_k(const float* __restrict__ adj,
                                                  int* __restrict__ deg,
                                                  int* __restrict__ nbr) {
    int row = blockIdx.x;
    int lane = threadIdx.x;  // 0..63
    const float* arow = adj + (size_t)row * NN;
    int count = 0;
    for (int base = 0; base < NN; base += 64) {
        float v = arow[base + lane];
        unsigned long long m = __ballot(v > 0.0f);
        if (v > 0.0f) {
            int pos = count + __popcll(m & ((1ull << lane) - 1ull));
            if (pos < MAXDEG) nbr[(size_t)row * MAXDEG + pos] = base + lane;
        }
        count += __popcll(m);
    }
    if (lane == 0) deg[row] = count < MAXDEG ? count : MAXDEG;
}

// ---------------- fp32 tiled GEMM: C[n, h*64+o] = sum_k A[n,k] * W[h,k,o] ----------------
// grid = (NH, NN/64); block = 256; 64x64 tile, 4x4 per thread, BK=32
__global__ __launch_bounds__(256) void gemm_wh_k(const float* __restrict__ A,
                                                 const float* __restrict__ W,
                                                 float* __restrict__ C,
                                                 int K) {
    __shared__ float As[64][33];   // [m][k], padded
    __shared__ float Bs[32][64];   // [k][o]
    const int tid = threadIdx.x;
    const int tx = tid & 15, ty = tid >> 4;
    const int row0 = blockIdx.y * 64;
    const int h = blockIdx.x;
    const int col0 = h * 64;
    const float* Wp = W + (size_t)h * K * FO;
    float acc[4][4] = {};
    for (int k0 = 0; k0 < K; k0 += 32) {
        #pragma unroll
        for (int it = 0; it < 8; ++it) {
            int idx = tid + it * 256;
            int m = idx >> 5, k = idx & 31;
            As[m][k] = A[(size_t)(row0 + m) * K + (k0 + k)];
        }
        #pragma unroll
        for (int it = 0; it < 8; ++it) {
            int idx = tid + it * 256;
            int k = idx >> 6, o = idx & 63;
            Bs[k][o] = Wp[(size_t)(k0 + k) * FO + o];
        }
        __syncthreads();
        #pragma unroll
        for (int k = 0; k < 32; ++k) {
            float av[4], bv[4];
            #pragma unroll
            for (int i = 0; i < 4; ++i) av[i] = As[ty * 4 + i][k];
            #pragma unroll
            for (int j = 0; j < 4; ++j) bv[j] = Bs[k][tx * 4 + j];
            #pragma unroll
            for (int i = 0; i < 4; ++i)
                #pragma unroll
                for (int j = 0; j < 4; ++j)
                    acc[i][j] = fmaf(av[i], bv[j], acc[i][j]);
        }
        __syncthreads();
    }
    #pragma unroll
    for (int i = 0; i < 4; ++i)
        #pragma unroll
        for (int j = 0; j < 4; ++j)
            C[(size_t)(row0 + ty * 4 + i) * FCAT + col0 + tx * 4 + j] = acc[i][j];
}

// ---------------- e_src/e_dst: one wave per (n,h), shuffle-reduce dot ----------------
__global__ __launch_bounds__(256) void compute_ee_k(const float* __restrict__ Wh,
                                                    const float* __restrict__ a,
                                                    float* __restrict__ esrc,
                                                    float* __restrict__ edst) {
    int wid = blockIdx.x * 4 + (threadIdx.x >> 6);
    int lane = threadIdx.x & 63;
    int n = wid >> 3, h = wid & 7;
    float w = Wh[(size_t)n * FCAT + h * FO + lane];
    float s = w * a[h * 2 * FO + lane];
    float d = w * a[h * 2 * FO + FO + lane];
    #pragma unroll
    for (int off = 32; off; off >>= 1) {
        s += __shfl_down(s, off);
        d += __shfl_down(d, off);
    }
    if (lane == 0) {
        esrc[h * NN + n] = s;
        edst[h * NN + n] = d;
    }
}

// ---------------- attention + aggregation: one wave per (n,h), lane = feature ----------------
__global__ __launch_bounds__(256) void attn_agg_k(const float* __restrict__ Wh,
                                                  const float* __restrict__ esrc,
                                                  const float* __restrict__ edst,
                                                  const int* __restrict__ deg,
                                                  const int* __restrict__ nbr,
                                                  float* __restrict__ outp) {
    __shared__ float pbuf[4][MAXDEG];
    __shared__ int jbuf[4][MAXDEG];
    const int ws = threadIdx.x >> 6;
    const int lane = threadIdx.x & 63;
    const int wid = blockIdx.x * 4 + ws;
    const int n = wid >> 3, h = wid & 7;
    const int d = deg[n];
    const int* nb = nbr + (size_t)n * MAXDEG;
    const float es = esrc[h * NN + n];

    for (int t = lane; t < d; t += 64) {
        int j = nb[t];
        float e = es + edst[h * NN + j];
        e = (e > 0.0f) ? e : ALPHA * e;
        jbuf[ws][t] = j;
        pbuf[ws][t] = e;
    }
    __syncthreads();
    float lm = -3.0e38f;
    for (int t = lane; t < d; t += 64) lm = fmaxf(lm, pbuf[ws][t]);
    #pragma unroll
    for (int off = 32; off; off >>= 1) lm = fmaxf(lm, __shfl_xor(lm, off));
    float lsum = 0.0f;
    for (int t = lane; t < d; t += 64) {
        float pv = __expf(pbuf[ws][t] - lm);
        pbuf[ws][t] = pv;
        lsum += pv;
    }
    #pragma unroll
    for (int off = 32; off; off >>= 1) lsum += __shfl_xor(lsum, off);
    __syncthreads();

    float acc = 0.0f;
    for (int t = 0; t < d; ++t) {
        int j = jbuf[ws][t];
        float pv = pbuf[ws][t];
        acc = fmaf(pv, Wh[(size_t)j * FCAT + h * FO + lane], acc);
    }
    acc /= lsum;
    float r = (acc > 0.0f) ? acc : (__expf(acc) - 1.0f);  // ELU
    outp[(size_t)n * FCAT + h * FO + lane] = r;
}

extern "C" void kernel_launch(void* const* d_in, const int* in_sizes, int n_in,
                              void* d_out, int out_size, void* d_ws, size_t ws_size,
                              hipStream_t stream) {
    const float* x   = (const float*)d_in[0];
    const float* adj = (const float*)d_in[1];
    const float* Wp[4] = {(const float*)d_in[2], (const float*)d_in[4],
                          (const float*)d_in[6], (const float*)d_in[8]};
    const float* ap[4] = {(const float*)d_in[3], (const float*)d_in[5],
                          (const float*)d_in[7], (const float*)d_in[9]};
    float* out = (float*)d_out;

    char* p = (char*)d_ws;
    int* deg = (int*)p;    p += (size_t)NN * sizeof(int);
    int* nbr = (int*)p;    p += (size_t)NN * MAXDEG * sizeof(int);
    float* hA = (float*)p; p += (size_t)NN * FCAT * sizeof(float);
    float* hB = (float*)p; p += (size_t)NN * FCAT * sizeof(float);
    float* Wh = (float*)p; p += (size_t)NN * FCAT * sizeof(float);
    float* esrc = (float*)p; p += (size_t)NN * NH * sizeof(float);
    float* edst = (float*)p; p += (size_t)NN * NH * sizeof(float);

    build_csr_k<<<NN, 64, 0, stream>>>(adj, deg, nbr);

    const float* in = x;
    int K = 128;
    float* outs[4] = {hA, hB, hA, out};
    for (int L = 0; L < 4; ++L) {
        dim3 g(NH, NN / 64);
        gemm_wh_k<<<g, 256, 0, stream>>>(in, Wp[L], Wh, K);
        compute_ee_k<<<NN * NH / 4, 256, 0, stream>>>(Wh, ap[L], esrc, edst);
        attn_agg_k<<<NN * NH / 4, 256, 0, stream>>>(Wh, esrc, edst, deg, nbr, outs[L]);
        in = outs[L];
        K = FCAT;
    }
}

// Round 2
// 168.610 us; speedup vs baseline: 1.4535x; 1.4535x over previous
//
#include <hip/hip_runtime.h>
#include <math.h>

#define NN 3072
#define NH 8
#define FO 64
#define FCAT 512
#define MAXDEG 128
#define ALPHA 0.2f

typedef __attribute__((ext_vector_type(8))) short bf16x8;
typedef __attribute__((ext_vector_type(4))) float f32x4;

static __device__ __forceinline__ unsigned short f2bf(float v) {
    union { float f; unsigned u; } x; x.f = v;
    unsigned r = x.u + 0x7fffu + ((x.u >> 16) & 1u);
    return (unsigned short)(r >> 16);
}
static __device__ __forceinline__ float bf2f(unsigned short b) {
    union { unsigned u; float f; } x; x.u = ((unsigned)b) << 16;
    return x.f;
}

// ---------------- CSR build: one wave per row, ballot-ordered (deterministic) ----------------
__global__ __launch_bounds__(64) void build_csr_k(const float* __restrict__ adj,
                                                  int* __restrict__ deg,
                                                  int* __restrict__ nbr) {
    int row = blockIdx.x;
    int lane = threadIdx.x;
    const float* arow = adj + (size_t)row * NN;
    int count = 0;
    for (int base = 0; base < NN; base += 64) {
        float v = arow[base + lane];
        unsigned long long m = __ballot(v > 0.0f);
        if (v > 0.0f) {
            int pos = count + __popcll(m & ((1ull << lane) - 1ull));
            if (pos < MAXDEG) nbr[(size_t)row * MAXDEG + pos] = base + lane;
        }
        count += __popcll(m);
    }
    if (lane == 0) deg[row] = count < MAXDEG ? count : MAXDEG;
}

// ---------------- x -> bf16 hi/lo ----------------
__global__ __launch_bounds__(256) void conv_x_k(const float* __restrict__ x,
                                                unsigned short* __restrict__ xh,
                                                unsigned short* __restrict__ xl, int n) {
    int i = blockIdx.x * 256 + threadIdx.x;
    if (i < n) {
        float v = x[i];
        unsigned short hb = f2bf(v);
        xh[i] = hb;
        xl[i] = f2bf(v - bf2f(hb));
    }
}

// ---------------- W[h][k][o] -> Wt[h][o][k] split to bf16 hi/lo (all 4 layers, one launch) ----
__global__ __launch_bounds__(256) void conv_wt_k(const float* __restrict__ W1,
                                                 const float* __restrict__ W2,
                                                 const float* __restrict__ W3,
                                                 const float* __restrict__ W4,
                                                 unsigned short* __restrict__ Wth,
                                                 unsigned short* __restrict__ Wtl) {
    __shared__ float t[64][65];
    int b = blockIdx.x;
    const float* W; int K; int local; size_t obase;
    if (b < 16)       { W = W1; K = 128; local = b;       obase = 0; }
    else if (b < 80)  { W = W2; K = 512; local = b - 16;  obase = 65536; }
    else if (b < 144) { W = W3; K = 512; local = b - 80;  obase = 327680; }
    else              { W = W4; K = 512; local = b - 144; obase = 589824; }
    int nkt = K >> 6;
    int h = local / nkt, kt = local - h * nkt;
    int k0 = kt * 64;
    int tid = threadIdx.x;
    for (int idx = tid; idx < 4096; idx += 256) {
        int r = idx >> 6, c = idx & 63;
        t[r][c] = W[(size_t)h * K * FO + (size_t)(k0 + r) * FO + c];
    }
    __syncthreads();
    for (int idx = tid; idx < 4096; idx += 256) {
        int o = idx >> 6, kk = idx & 63;
        float v = t[kk][o];
        unsigned short hb = f2bf(v);
        size_t dst = obase + (size_t)(h * FO + o) * K + k0 + kk;
        Wth[dst] = hb;
        Wtl[dst] = f2bf(v - bf2f(hb));
    }
}

// ---------------- split-bf16 MFMA GEMM: C[n, h*64+o] = A[n,:] . Wt[h][o][:] ----------------
// grid (NH, NN/64); block 256 = 4 waves of 32x32 output each; BK=64
__global__ __launch_bounds__(256) void gemm_mfma_k(const unsigned short* __restrict__ Ah,
                                                   const unsigned short* __restrict__ Al,
                                                   const unsigned short* __restrict__ Bh,
                                                   const unsigned short* __restrict__ Bl,
                                                   float* __restrict__ C, int K) {
    __shared__ unsigned short As[2][64][80];   // [hi/lo][row][k], chunk-XOR swizzled
    __shared__ unsigned short Bs[2][64][80];   // [hi/lo][col][k]
    const int tid = threadIdx.x;
    const int h = blockIdx.x;
    const int r0 = blockIdx.y * 64;
    const int lane = tid & 63;
    const int wid = tid >> 6;
    const int wr = wid >> 1, wc = wid & 1;
    const int lr = lane & 15, lg = lane >> 4;

    const unsigned short* Bhh = Bh + (size_t)h * FO * K;
    const unsigned short* Bll = Bl + (size_t)h * FO * K;

    f32x4 acc[2][2];
    #pragma unroll
    for (int i = 0; i < 2; ++i)
        #pragma unroll
        for (int j = 0; j < 2; ++j) acc[i][j] = (f32x4){0.f, 0.f, 0.f, 0.f};

    for (int k0 = 0; k0 < K; k0 += 64) {
        #pragma unroll
        for (int half = 0; half < 2; ++half) {
            int q = tid + half * 256;
            int row = q >> 3, cq = q & 7;
            int sw = (cq ^ (row & 7)) * 8;
            size_t ga = (size_t)(r0 + row) * K + k0 + cq * 8;
            *(bf16x8*)&As[0][row][sw] = *(const bf16x8*)(Ah + ga);
            *(bf16x8*)&As[1][row][sw] = *(const bf16x8*)(Al + ga);
            size_t gb = (size_t)row * K + k0 + cq * 8;
            *(bf16x8*)&Bs[0][row][sw] = *(const bf16x8*)(Bhh + gb);
            *(bf16x8*)&Bs[1][row][sw] = *(const bf16x8*)(Bll + gb);
        }
        __syncthreads();
        #pragma unroll
        for (int ks = 0; ks < 2; ++ks) {
            bf16x8 ah[2], al[2], bh[2], bl[2];
            #pragma unroll
            for (int i = 0; i < 2; ++i) {
                int cq = ks * 4 + lg;
                int row = wr * 32 + i * 16 + lr;
                int offa = (cq ^ (row & 7)) * 8;
                ah[i] = *(const bf16x8*)&As[0][row][offa];
                al[i] = *(const bf16x8*)&As[1][row][offa];
                int col = wc * 32 + i * 16 + lr;
                int offb = (cq ^ (col & 7)) * 8;
                bh[i] = *(const bf16x8*)&Bs[0][col][offb];
                bl[i] = *(const bf16x8*)&Bs[1][col][offb];
            }
            #pragma unroll
            for (int i = 0; i < 2; ++i)
                #pragma unroll
                for (int j = 0; j < 2; ++j) {
                    acc[i][j] = __builtin_amdgcn_mfma_f32_16x16x32_bf16(ah[i], bh[j], acc[i][j], 0, 0, 0);
                    acc[i][j] = __builtin_amdgcn_mfma_f32_16x16x32_bf16(ah[i], bl[j], acc[i][j], 0, 0, 0);
                    acc[i][j] = __builtin_amdgcn_mfma_f32_16x16x32_bf16(al[i], bh[j], acc[i][j], 0, 0, 0);
                }
        }
        __syncthreads();
    }
    #pragma unroll
    for (int i = 0; i < 2; ++i)
        #pragma unroll
        for (int j = 0; j < 2; ++j)
            #pragma unroll
            for (int r = 0; r < 4; ++r) {
                int row = r0 + wr * 32 + i * 16 + lg * 4 + r;
                int col = h * FO + wc * 32 + j * 16 + lr;
                C[(size_t)row * FCAT + col] = acc[i][j][r];
            }
}

// ---------------- e_src/e_dst: one wave per (n,h) ----------------
__global__ __launch_bounds__(256) void compute_ee_k(const float* __restrict__ Wh,
                                                    const float* __restrict__ a,
                                                    float* __restrict__ esrc,
                                                    float* __restrict__ edst) {
    int wid = blockIdx.x * 4 + (threadIdx.x >> 6);
    int lane = threadIdx.x & 63;
    int n = wid >> 3, h = wid & 7;
    float w = Wh[(size_t)n * FCAT + h * FO + lane];
    float s = w * a[h * 2 * FO + lane];
    float d = w * a[h * 2 * FO + FO + lane];
    #pragma unroll
    for (int off = 32; off; off >>= 1) {
        s += __shfl_down(s, off);
        d += __shfl_down(d, off);
    }
    if (lane == 0) {
        esrc[h * NN + n] = s;
        edst[h * NN + n] = d;
    }
}

// ---------------- attention + aggregation + ELU (+ bf16 hi/lo epilogue) ----------------
__global__ __launch_bounds__(256) void attn_agg_k(const float* __restrict__ Wh,
                                                  const float* __restrict__ esrc,
                                                  const float* __restrict__ edst,
                                                  const int* __restrict__ deg,
                                                  const int* __restrict__ nbr,
                                                  float* __restrict__ outp,
                                                  unsigned short* __restrict__ oh,
                                                  unsigned short* __restrict__ ol,
                                                  int write_f32) {
    __shared__ float pbuf[4][MAXDEG];
    __shared__ int jbuf[4][MAXDEG];
    const int ws = threadIdx.x >> 6;
    const int lane = threadIdx.x & 63;
    const int wid = blockIdx.x * 4 + ws;
    const int n = wid >> 3, h = wid & 7;
    const int d = deg[n];
    const int* nb = nbr + (size_t)n * MAXDEG;
    const float es = esrc[h * NN + n];

    for (int t = lane; t < d; t += 64) {
        int j = nb[t];
        float e = es + edst[h * NN + j];
        e = (e > 0.0f) ? e : ALPHA * e;
        jbuf[ws][t] = j;
        pbuf[ws][t] = e;
    }
    __syncthreads();
    float lm = -3.0e38f;
    for (int t = lane; t < d; t += 64) lm = fmaxf(lm, pbuf[ws][t]);
    #pragma unroll
    for (int off = 32; off; off >>= 1) lm = fmaxf(lm, __shfl_xor(lm, off));
    float lsum = 0.0f;
    for (int t = lane; t < d; t += 64) {
        float pv = __expf(pbuf[ws][t] - lm);
        pbuf[ws][t] = pv;
        lsum += pv;
    }
    #pragma unroll
    for (int off = 32; off; off >>= 1) lsum += __shfl_xor(lsum, off);
    __syncthreads();

    float acc = 0.0f;
    for (int t = 0; t < d; ++t) {
        int j = jbuf[ws][t];
        float pv = pbuf[ws][t];
        acc = fmaf(pv, Wh[(size_t)j * FCAT + h * FO + lane], acc);
    }
    acc /= lsum;
    float r = (acc > 0.0f) ? acc : (__expf(acc) - 1.0f);  // ELU
    size_t idx = (size_t)n * FCAT + h * FO + lane;
    if (write_f32) {
        outp[idx] = r;
    } else {
        unsigned short hb = f2bf(r);
        oh[idx] = hb;
        ol[idx] = f2bf(r - bf2f(hb));
    }
}

extern "C" void kernel_launch(void* const* d_in, const int* in_sizes, int n_in,
                              void* d_out, int out_size, void* d_ws, size_t ws_size,
                              hipStream_t stream) {
    const float* x   = (const float*)d_in[0];
    const float* adj = (const float*)d_in[1];
    const float* ap[4] = {(const float*)d_in[3], (const float*)d_in[5],
                          (const float*)d_in[7], (const float*)d_in[9]};
    float* out = (float*)d_out;

    char* p = (char*)d_ws;
    int* deg = (int*)p;              p += (size_t)NN * sizeof(int);            // 12 KB
    int* nbr = (int*)p;              p += (size_t)NN * MAXDEG * sizeof(int);   // 1.5 MB
    unsigned short* Ah = (unsigned short*)p; p += (size_t)NN * FCAT * 2;       // 3 MB
    unsigned short* Al = (unsigned short*)p; p += (size_t)NN * FCAT * 2;       // 3 MB
    float* WhF = (float*)p;          p += (size_t)NN * FCAT * sizeof(float);   // 6 MB
    unsigned short* Wth = (unsigned short*)p; p += (size_t)851968 * 2;         // 1.7 MB
    unsigned short* Wtl = (unsigned short*)p; p += (size_t)851968 * 2;         // 1.7 MB
    float* esrc = (float*)p;         p += (size_t)NN * NH * sizeof(float);
    float* edst = (float*)p;         p += (size_t)NN * NH * sizeof(float);

    build_csr_k<<<NN, 64, 0, stream>>>(adj, deg, nbr);
    conv_x_k<<<(NN * 128 + 255) / 256, 256, 0, stream>>>(x, Ah, Al, NN * 128);
    conv_wt_k<<<208, 256, 0, stream>>>((const float*)d_in[2], (const float*)d_in[4],
                                       (const float*)d_in[6], (const float*)d_in[8],
                                       Wth, Wtl);

    const size_t woff[4] = {0, 65536, 327680, 589824};
    int K = 128;
    for (int L = 0; L < 4; ++L) {
        dim3 g(NH, NN / 64);
        gemm_mfma_k<<<g, 256, 0, stream>>>(Ah, Al, Wth + woff[L], Wtl + woff[L], WhF, K);
        compute_ee_k<<<NN * NH / 4, 256, 0, stream>>>(WhF, ap[L], esrc, edst);
        attn_agg_k<<<NN * NH / 4, 256, 0, stream>>>(WhF, esrc, edst, deg, nbr,
                                                    out, Ah, Al, L == 3 ? 1 : 0);
        K = FCAT;
    }
}